// Round 1
// baseline (462.742 us; speedup 1.0000x reference)
//
#include <hip/hip_runtime.h>

// Problem constants (from reference): T=1024, B=128, C=256, L=64
#define NEG (-1e30f)
constexpr int T = 1024;
constexpr int B = 128;
constexpr int C = 256;
constexpr int L = 64;
constexpr int S = 2 * L + 1;      // 129 DP states
constexpr int SEL_STRIDE = 66;    // 65 gathered classes (blank + 64 labels) + 1 pad
constexpr int P1_GRID = 2048;     // phase-1 blocks (b fixed per block, t strided by 16)
constexpr int CH = 32;            // t-chunk staged into LDS per phase-2 step
constexpr int NSTG = (CH * SEL_STRIDE + 255) / 256;  // staging regs per thread = 9

// ---------------------------------------------------------------------------
// Phase 1: coalesced read of log_probs; entropy partial per block (no atomics);
// gather blank+label log-probs into compacted sel[b][t][66] for the DP.
// ---------------------------------------------------------------------------
__global__ __launch_bounds__(256) void phase1_entropy_gather(
    const float* __restrict__ lp, const int* __restrict__ targets,
    float* __restrict__ sel, float* __restrict__ ent_part, int do_sel) {
  const int tid = threadIdx.x;
  const int bid = blockIdx.x;
  const int b = bid & (B - 1);   // fixed per block (grid stride 2048 ≡ 0 mod 128)
  const int t0 = bid >> 7;       // in [0,16)

  int cls = 0;
  if (tid > 0 && tid < 65) cls = targets[b * L + tid - 1];

  float ent = 0.f;
  for (int k = 0; k < T / 16; ++k) {
    const int t = t0 + k * 16;
    const size_t rowoff = ((size_t)t * B + b) * C;
    const float v = lp[rowoff + tid];           // coalesced 1 KiB row
    ent += v * __expf(v);
    if (do_sel && tid < 65) {
      const float g = lp[rowoff + cls];         // L1-hit re-read of same row
      sel[((size_t)b * T + t) * SEL_STRIDE + tid] = g;
    }
  }
  // block entropy reduction -> deterministic per-block partial
  for (int off = 32; off > 0; off >>= 1) ent += __shfl_down(ent, off, 64);
  __shared__ float wsum[4];
  const int wave = tid >> 6, lane = tid & 63;
  if (lane == 0) wsum[wave] = ent;
  __syncthreads();
  if (tid == 0) ent_part[bid] = wsum[0] + wsum[1] + wsum[2] + wsum[3];
}

// ---------------------------------------------------------------------------
// Phase 2: one block per batch element. CTC forward DP, alpha double-buffered
// in LDS, lp chunks double-buffered in LDS with register prefetch one chunk
// ahead. Early exit at t = input_len-1.
// ---------------------------------------------------------------------------
__global__ __launch_bounds__(256) void phase2_ctc_dp(
    const float* __restrict__ lp, const float* __restrict__ sel,
    const int* __restrict__ targets, const int* __restrict__ in_len,
    const int* __restrict__ tg_len, float* __restrict__ nll_out, int use_sel) {
  const int b = blockIdx.x;
  const int tid = threadIdx.x;
  const int len = in_len[b];
  const int tl = tg_len[b];

  __shared__ float lpbuf[2][CH * SEL_STRIDE];
  __shared__ float albuf[2][S + 2];   // [0],[1] = NEG sentinels

  // Per-thread DP constants: lp column index + skip-transition mask
  int jj = 0;
  bool allow2 = false;
  if (tid < S && (tid & 1)) {
    jj = 1 + (tid >> 1);                         // label (tid-1)/2
    const int cur = targets[b * L + ((tid - 1) >> 1)];
    allow2 = (tid == 1) ? true : (cur != targets[b * L + ((tid - 3) >> 1)]);
  }
  if (tid < 2) { albuf[0][tid] = NEG; albuf[1][tid] = NEG; }

  const float* selB = sel + (size_t)b * T * SEL_STRIDE;
  auto stage_val = [&](int c, int i) -> float {
    if (use_sel) return selB[(size_t)c * CH * SEL_STRIDE + i];  // contiguous
    const int t = c * CH + i / SEL_STRIDE;
    const int j = i % SEL_STRIDE;
    if (j >= 65) return NEG;
    const int cl = (j == 0) ? 0 : targets[b * L + j - 1];
    return lp[((size_t)t * B + b) * C + cl];
  };

  // Preload chunk 0 directly into LDS (one-time stall)
#pragma unroll
  for (int k = 0; k < NSTG; ++k) {
    const int i = tid + k * 256;
    if (i < CH * SEL_STRIDE) lpbuf[0][i] = stage_val(0, i);
  }
  __syncthreads();

  const int nch = (len + CH - 1) / CH;
  int p = 0;
  for (int c = 0; c < nch; ++c) {
    // Issue next chunk's global loads into registers (latency hidden by DP loop)
    float st[NSTG];
    const bool havenext = (c + 1 < nch);
    if (havenext) {
#pragma unroll
      for (int k = 0; k < NSTG; ++k) {
        const int i = tid + k * 256;
        st[k] = (i < CH * SEL_STRIDE) ? stage_val(c + 1, i) : 0.f;
      }
    }
    const int tend = min(CH, len - c * CH);
    const float* lpc = lpbuf[c & 1];
    for (int toff = 0; toff < tend; ++toff) {
      const int t = c * CH + toff;
      if (tid < S) {
        const float lpv = lpc[toff * SEL_STRIDE + jj];
        float aNew;
        if (t == 0) {
          aNew = (tid < 2) ? lpv : NEG;   // alpha0
        } else {
          const float a  = albuf[p][tid + 2];
          const float p1 = albuf[p][tid + 1];
          const float p2 = allow2 ? albuf[p][tid] : NEG;
          const float m = fmaxf(a, fmaxf(p1, p2));
          const float sum = __expf(a - m) + __expf(p1 - m) + __expf(p2 - m);
          aNew = m + __logf(sum) + lpv;
        }
        albuf[p ^ 1][tid + 2] = aNew;
      }
      __syncthreads();
      p ^= 1;
    }
    if (havenext) {
#pragma unroll
      for (int k = 0; k < NSTG; ++k) {
        const int i = tid + k * 256;
        if (i < CH * SEL_STRIDE) lpbuf[(c + 1) & 1][i] = st[k];
      }
      __syncthreads();  // staged chunk visible before next chunk's reads
    }
  }

  if (tid == 0) {
    const float a1 = albuf[p][2 * tl + 2];     // state 2*tl (offset +2)
    const float a0 = albuf[p][2 * tl + 1];     // state 2*tl-1
    const float m = fmaxf(a1, a0);
    const float ll = m + __logf(__expf(a1 - m) + __expf(a0 - m));
    float nll = -ll;
    if (nll > 1e29f) nll = 0.f;                // zero_infinity
    nll_out[b] = nll;
  }
}

// ---------------------------------------------------------------------------
// Phase 3: combine 2048 entropy partials + 128 NLLs into the scalar loss.
// ---------------------------------------------------------------------------
__global__ __launch_bounds__(256) void phase3_final(
    const float* __restrict__ ent_part, const float* __restrict__ nll,
    float* __restrict__ out) {
  const int tid = threadIdx.x;
  float s = 0.f;
  for (int i = tid; i < P1_GRID; i += 256) s += ent_part[i];
  float n = (tid < B) ? nll[tid] : 0.f;
  for (int off = 32; off > 0; off >>= 1) {
    s += __shfl_down(s, off, 64);
    n += __shfl_down(n, off, 64);
  }
  __shared__ float ss[4], nn[4];
  const int wave = tid >> 6, lane = tid & 63;
  if (lane == 0) { ss[wave] = s; nn[wave] = n; }
  __syncthreads();
  if (tid == 0) {
    const float ent_sum = ss[0] + ss[1] + ss[2] + ss[3];
    const float nll_sum = nn[0] + nn[1] + nn[2] + nn[3];
    const float ctc_mean = nll_sum / (float)B;
    const float smooth = ent_sum / (float)(T * B);  // = -entropy.mean()
    out[0] = 0.9f * ctc_mean + 0.1f * smooth;
  }
}

extern "C" void kernel_launch(void* const* d_in, const int* in_sizes, int n_in,
                              void* d_out, int out_size, void* d_ws, size_t ws_size,
                              hipStream_t stream) {
  const float* lp      = (const float*)d_in[0];  // [T,B,C] f32
  const int*   targets = (const int*)d_in[1];    // [B,L] i32
  const int*   in_len  = (const int*)d_in[2];    // [B] i32
  const int*   tg_len  = (const int*)d_in[3];    // [B] i32
  float* out = (float*)d_out;
  float* ws  = (float*)d_ws;

  float* ent_part = ws;                 // [2048]
  float* nllb     = ws + P1_GRID;       // [128]
  float* sel      = ws + P1_GRID + 256; // [B*T*66], 16B-aligned offset

  const size_t need =
      ((size_t)(P1_GRID + 256) + (size_t)B * T * SEL_STRIDE) * sizeof(float);
  const int use_sel = (ws_size >= need) ? 1 : 0;

  phase1_entropy_gather<<<P1_GRID, 256, 0, stream>>>(
      lp, targets, use_sel ? sel : nullptr, ent_part, use_sel);
  phase2_ctc_dp<<<B, 256, 0, stream>>>(
      lp, sel, targets, in_len, tg_len, nllb, use_sel);
  phase3_final<<<1, 256, 0, stream>>>(ent_part, nllb, out);
}